// Round 7
// baseline (408.922 us; speedup 1.0000x reference)
//
#include <hip/hip_runtime.h>
#include <hip/hip_bf16.h>

// MoE top-2, T=32768 tokens, D=1024, E=8.
// Pipeline: gate(4 tok/wave) -> hist -> scan -> scatter(+inverse map) -> wconv
//           -> grouped GEMM (256^2, BK=64, read-ahead counted-vmcnt pipeline) -> combine.

typedef __attribute__((ext_vector_type(8))) short short8_t;
typedef __attribute__((ext_vector_type(4))) float f32x4_t;

#define GLOAD_LDS16(g, l)                                                                     \
  __builtin_amdgcn_global_load_lds((const __attribute__((address_space(1))) unsigned int*)(g), \
                                   (__attribute__((address_space(3))) unsigned int*)(l), 16, 0, 0)

__device__ __forceinline__ unsigned short f2bf(float f) {
  union { __hip_bfloat16 h; unsigned short u; } c;
  c.h = __float2bfloat16(f);
  return c.u;
}

// ---------------- gate: 4 tokens/wave; fp32 logits, top-2 softmax; x -> bf16 ----------------
__global__ __launch_bounds__(256) void gate_kernel(
    const float* __restrict__ x, const float* __restrict__ gw,
    unsigned short* __restrict__ xb,
    int* __restrict__ tok_e, float* __restrict__ tok_w)
{
  int wid = threadIdx.x >> 6, lane = threadIdx.x & 63;
  int t0 = (blockIdx.x << 4) + (wid << 2);              // 4 tokens per wave
  const float4* g4 = (const float4*)gw;                 // gw is [1024][8] row-major
  float lg[4][8] = {};
  #pragma unroll
  for (int c = 0; c < 4; ++c) {
    int d4 = (c << 6) + lane;                           // float4 index within a row
    float4 ga[4], gb[4];
    #pragma unroll
    for (int j = 0; j < 4; ++j) {
      int d = (d4 << 2) + j;
      ga[j] = g4[d << 1];
      gb[j] = g4[(d << 1) + 1];
    }
    #pragma unroll
    for (int t = 0; t < 4; ++t) {                       // reuse gw regs across 4 tokens
      const float4* x4 = (const float4*)(x + ((size_t)(t0 + t) << 10));
      float4 v = x4[d4];
      unsigned long long pk = (unsigned long long)f2bf(v.x)
                            | ((unsigned long long)f2bf(v.y) << 16)
                            | ((unsigned long long)f2bf(v.z) << 32)
                            | ((unsigned long long)f2bf(v.w) << 48);
      ((unsigned long long*)(xb + ((size_t)(t0 + t) << 10)))[d4] = pk;
      float xs[4] = {v.x, v.y, v.z, v.w};
      #pragma unroll
      for (int j = 0; j < 4; ++j) {
        lg[t][0] += xs[j]*ga[j].x; lg[t][1] += xs[j]*ga[j].y;
        lg[t][2] += xs[j]*ga[j].z; lg[t][3] += xs[j]*ga[j].w;
        lg[t][4] += xs[j]*gb[j].x; lg[t][5] += xs[j]*gb[j].y;
        lg[t][6] += xs[j]*gb[j].z; lg[t][7] += xs[j]*gb[j].w;
      }
    }
  }
  #pragma unroll
  for (int t = 0; t < 4; ++t)
    #pragma unroll
    for (int e = 0; e < 8; ++e) {
      float v = lg[t][e];
      #pragma unroll
      for (int s = 32; s > 0; s >>= 1) v += __shfl_xor(v, s, 64);
      lg[t][e] = v;
    }
  if (lane < 4) {                                       // lane t finalizes token t0+t
    int t = t0 + lane;
    float m0 = lg[lane][0], m1 = -3.4e38f; int e0 = 0, e1 = 0;
    #pragma unroll
    for (int e = 1; e < 8; ++e) {                       // strict '>' matches jax top_k ties
      float v = lg[lane][e];
      if (v > m0) { m1 = m0; e1 = e0; m0 = v; e0 = e; }
      else if (v > m1) { m1 = v; e1 = e; }
    }
    float p1 = 1.0f / (1.0f + expf(m0 - m1));
    float p0 = 1.0f - p1;
    int i0 = t << 1;
    tok_e[i0]   = e0; tok_w[i0]   = p0;
    tok_e[i0+1] = e1; tok_w[i0+1] = p1;
  }
}

// ---------------- hist: per-256-entry chunk, LDS histogram + local rank ----------------
__global__ __launch_bounds__(256) void hist_kernel(
    const int* __restrict__ tok_e, int* __restrict__ tok_r, int* __restrict__ chunkhist)
{
  __shared__ int lh[8];
  if (threadIdx.x < 8) lh[threadIdx.x] = 0;
  __syncthreads();
  int i = (blockIdx.x << 8) + threadIdx.x;
  int e = tok_e[i];
  tok_r[i] = atomicAdd(&lh[e], 1);
  __syncthreads();
  if (threadIdx.x < 8) chunkhist[(blockIdx.x << 3) + threadIdx.x] = lh[threadIdx.x];
}

// ---------------- scan: 8 waves, wave e scans expert e across 256 chunks ----------------
__global__ __launch_bounds__(512) void scan_kernel(
    const int* __restrict__ chunkhist, int* __restrict__ base, int* __restrict__ ctrl)
{
  __shared__ int h[2048];
  __shared__ int bx[2048];
  __shared__ int tot[8], eoff[8];
  for (int i = threadIdx.x; i < 2048; i += 512) h[i] = chunkhist[i];
  __syncthreads();
  int wid = threadIdx.x >> 6, lane = threadIdx.x & 63;
  int running = 0;
  #pragma unroll
  for (int b = 0; b < 4; ++b) {
    int c = (b << 6) + lane;
    int orig = h[(c << 3) + wid];
    int v = orig;
    #pragma unroll
    for (int s = 1; s < 64; s <<= 1) {
      int u = __shfl_up(v, s, 64);
      if (lane >= s) v += u;
    }
    bx[(c << 3) + wid] = running + v - orig;            // exclusive, expert-local
    running += __shfl(v, 63, 64);
  }
  if (lane == 0) tot[wid] = running;
  __syncthreads();
  if (threadIdx.x == 0) {
    int off = 0, boff = 0;
    #pragma unroll
    for (int e = 0; e < 8; ++e) {
      ctrl[e] = tot[e];
      ctrl[8 + e] = off; eoff[e] = off; off += tot[e];
      ctrl[16 + e] = boff; boff += (tot[e] + 255) >> 8;  // 256-row M-groups
    }
    ctrl[24] = boff;
  }
  __syncthreads();
  for (int i = threadIdx.x; i < 2048; i += 512) base[i] = bx[i] + eoff[i & 7];
}

// ---------------- scatter (t,k) -> dense slots + inverse map ----------------
__global__ __launch_bounds__(256) void scatter_kernel(
    const int* __restrict__ tok_e, const int* __restrict__ tok_r, const float* __restrict__ tok_w,
    const int* __restrict__ base, int* __restrict__ slot_token, float* __restrict__ slot_w,
    int* __restrict__ tok_slot)
{
  int i = (blockIdx.x << 8) + threadIdx.x;
  int e = tok_e[i];
  int slot = base[((i >> 8) << 3) + e] + tok_r[i];
  slot_token[slot] = i >> 1;
  slot_w[slot] = tok_w[i];
  tok_slot[i] = slot;
}

// ---------------- expert_w fp32 [e][k][n] -> bf16 transposed Wt[e][n][k] ----------------
__global__ __launch_bounds__(256) void wconv_kernel(const float* __restrict__ w,
                                                    unsigned short* __restrict__ wt)
{
  __shared__ float tile[32][33];
  const float* we = w + ((size_t)blockIdx.z << 20);
  unsigned short* wte = wt + ((size_t)blockIdx.z << 20);
  int k0 = blockIdx.x << 5, n0 = blockIdx.y << 5;
  for (int i = threadIdx.x; i < 1024; i += 256) {
    int k = i >> 5, n = i & 31;
    tile[k][n] = we[(size_t)(k0 + k) * 1024 + n0 + n];
  }
  __syncthreads();
  for (int i = threadIdx.x; i < 1024; i += 256) {
    int n = i >> 5, k = i & 31;
    wte[(size_t)(n0 + n) * 1024 + k0 + k] = f2bf(tile[k][n]);
  }
}

// ---------------- grouped GEMM: 256x256, BK=64, 8 waves, read-ahead pipeline ----------
// Per tile t (buf tb), phases (each: {reads/stages BEFORE barrier, MFMA after}):
//  P0: issue B(t+1); read bF0(tb);            BAR; Q00(aN,bF0);  BAR
//  P1:               read bF1(tb);            BAR; Q01(aN,bF1);  BAR
//  P2:               read aF1(tb); vmcnt(4);  BAR; Q11(aF1,bF1); BAR   <- publishes A(t+1)
//  P3: issue A(t+2); vmcnt(4); read aN(ntb);  BAR; Q10(aF1,bF0); BAR   <- publishes B(t+1)
// Loads stay 4-8 outstanding; vmcnt never drains to 0 in the loop. Publication rule:
// freshly staged LDS is only read after every wave's vmcnt + a barrier.
// LDS slot s of row r holds global 16B k-block (s ^ (r&7)); both-sides swizzle.
__global__ __launch_bounds__(512, 2) void moe_gemm(
    const unsigned short* __restrict__ xb, const unsigned short* __restrict__ wt,
    const float* __restrict__ bias, const int* __restrict__ ctrl,
    const int* __restrict__ slot_token, const float* __restrict__ slot_w,
    float* __restrict__ ybuf, float* __restrict__ out, int total_slots, int use_ybuf)
{
  __shared__ unsigned short Alds[2 * 256 * 64];   // 64 KB: [buf][row][k]
  __shared__ unsigned short Blds[2 * 256 * 64];   // 64 KB
  __shared__ int   tokid[256];
  __shared__ float wrow[256];

  // dispatch map: 4 N-blocks of an M-group share one XCD (d&7)
  int d = blockIdx.x;
  int xcd = d & 7, nb = (d >> 3) & 3, gbase = d >> 5;
  int by = (gbase << 3) | xcd;                    // M-group id
  if (by >= ctrl[24]) return;
  int e = 0;
  #pragma unroll
  for (int i = 1; i < 8; ++i) if (by >= ctrl[16 + i]) e = i;
  int mblk = by - ctrl[16 + e];
  int cnt  = ctrl[e];
  int slot0 = ctrl[8 + e] + (mblk << 8);
  int rows_valid = cnt - (mblk << 8); if (rows_valid > 256) rows_valid = 256;

  int tid = threadIdx.x;
  if (tid < 256) {
    int s = slot0 + tid; if (s > total_slots - 1) s = total_slots - 1;
    tokid[tid] = slot_token[s];
    wrow[tid]  = slot_w[s];
  }
  __syncthreads();                                 // prologue only: no loads in flight yet

  int lane = tid & 63, w = tid >> 6;
  int wm = w >> 2, wn = w & 3;                     // wave grid 2M x 4N
  int l15 = lane & 15, hk = lane >> 4;
  int bn0 = nb << 8;
  const unsigned short* wte = wt + ((size_t)e << 20);

  // staging: thread covers LDS row (tid>>3) per quarter j, 16B slot (tid&7);
  // source k-block pre-swizzled by row&7 so linear GLDS dest yields swizzled layout.
  int rsub = tid >> 3;                             // 0..63
  int kswz = (tid & 7) ^ (rsub & 7);
  const unsigned short* As[4];
  const unsigned short* Bs[4];
  #pragma unroll
  for (int j = 0; j < 4; ++j) {
    As[j] = xb  + ((size_t)tokid[(j << 6) + rsub] << 10) + (kswz << 3);
    Bs[j] = wte + ((size_t)(bn0 + (j << 6) + rsub) << 10) + (kswz << 3);
  }

  f32x4_t acc[8][4] = {};
  short8_t aN[4][2], aF1[4][2], bF0[2][2], bF1[2][2];

#define LDSA(base, ar, kk) (*(const short8_t*)&Alds[(base) + ((ar) << 6) + (((((kk) << 2) + hk) ^ ((ar) & 7)) << 3)])
#define LDSB(base, br, kk) (*(const short8_t*)&Blds[(base) + ((br) << 6) + (((((kk) << 2) + hk) ^ ((br) & 7)) << 3)])
#define QUAD(AF, BF, MB, NB)                                                            \
  _Pragma("unroll") for (int mf = 0; mf < 4; ++mf)                                      \
  _Pragma("unroll") for (int nf = 0; nf < 2; ++nf)                                      \
  _Pragma("unroll") for (int kk = 0; kk < 2; ++kk)                                      \
    acc[(MB)*4+mf][(NB)*2+nf] = __builtin_amdgcn_mfma_f32_16x16x32_bf16(                \
        AF[mf][kk], BF[nf][kk], acc[(MB)*4+mf][(NB)*2+nf], 0, 0, 0);
#define RD_A(DST, base, mh)                                                             \
  _Pragma("unroll") for (int mf = 0; mf < 4; ++mf)                                      \
  _Pragma("unroll") for (int kk = 0; kk < 2; ++kk)                                      \
    DST[mf][kk] = LDSA(base, (wm << 7) + ((mh) << 6) + (mf << 4) + l15, kk);
#define RD_B(DST, base, nh)                                                             \
  _Pragma("unroll") for (int nf = 0; nf < 2; ++nf)                                      \
  _Pragma("unroll") for (int kk = 0; kk < 2; ++kk)                                      \
    DST[nf][kk] = LDSB(base, (wn << 6) + ((nh) << 5) + (nf << 4) + l15, kk);

  // prologue: stage A(0),B(0)->buf0, A(1)->buf1; publish A(0)+B(0); pre-read aN(buf0)
  #pragma unroll
  for (int j = 0; j < 4; ++j) GLOAD_LDS16(As[j], &Alds[(j << 12) + (w << 9)]);
  #pragma unroll
  for (int j = 0; j < 4; ++j) GLOAD_LDS16(Bs[j], &Blds[(j << 12) + (w << 9)]);
  #pragma unroll
  for (int j = 0; j < 4; ++j) GLOAD_LDS16(As[j] + 64, &Alds[16384 + (j << 12) + (w << 9)]);
  asm volatile("s_waitcnt vmcnt(4)" ::: "memory");   // A(0),B(0) landed; A(1) in flight
  __builtin_amdgcn_s_barrier();
  RD_A(aN, 0, 0)

  int tb = 0;
  for (int t = 0; t < 15; ++t) {
    int ntb = tb ^ 16384;
    // ---- P0: issue B(t+1)->ntb; read bF0(tb); BAR; Q00 ----
    {
      int koffB = (t + 1) << 6;
      #pragma unroll
      for (int j = 0; j < 4; ++j)
        GLOAD_LDS16(Bs[j] + koffB, &Blds[ntb + (j << 12) + (w << 9)]);
    }
    RD_B(bF0, tb, 0)
    __builtin_amdgcn_sched_barrier(0);
    __builtin_amdgcn_s_barrier();
    __builtin_amdgcn_s_setprio(1);
    QUAD(aN, bF0, 0, 0)
    __builtin_amdgcn_s_setprio(0);
    __builtin_amdgcn_s_barrier();
    // ---- P1: read bF1(tb); BAR; Q01 ----
    RD_B(bF1, tb, 1)
    __builtin_amdgcn_sched_barrier(0);
    __builtin_amdgcn_s_barrier();
    __builtin_amdgcn_s_setprio(1);
    QUAD(aN, bF1, 0, 1)
    __builtin_amdgcn_s_setprio(0);
    __builtin_amdgcn_s_barrier();
    // ---- P2: read aF1(tb); vmcnt(4) [A(t+1) publish at BAR]; BAR; Q11 ----
    RD_A(aF1, tb, 1)
    asm volatile("s_waitcnt vmcnt(4)" ::: "memory");
    __builtin_amdgcn_sched_barrier(0);
    __builtin_amdgcn_s_barrier();
    __builtin_amdgcn_s_setprio(1);
    QUAD(aF1, bF1, 1, 1)
    __builtin_amdgcn_s_setprio(0);
    __builtin_amdgcn_s_barrier();
    // ---- P3: issue A(t+2)->tb; vmcnt(4) [B(t+1) publish]; read aN(ntb); BAR; Q10 ----
    if (t < 14) {
      int koffA = (t + 2) << 6;
      #pragma unroll
      for (int j = 0; j < 4; ++j)
        GLOAD_LDS16(As[j] + koffA, &Alds[tb + (j << 12) + (w << 9)]);
    }
    asm volatile("s_waitcnt vmcnt(4)" ::: "memory");
    RD_A(aN, ntb, 0)
    __builtin_amdgcn_sched_barrier(0);
    __builtin_amdgcn_s_barrier();
    __builtin_amdgcn_s_setprio(1);
    QUAD(aF1, bF0, 1, 0)
    __builtin_amdgcn_s_setprio(0);
    __builtin_amdgcn_s_barrier();
    tb = ntb;
  }
  // ---- peeled tile 15: publish B(15); read rest; 4 quads ----
  asm volatile("s_waitcnt vmcnt(0)" ::: "memory");
  __builtin_amdgcn_s_barrier();
  RD_B(bF0, tb, 0)
  RD_B(bF1, tb, 1)
  RD_A(aF1, tb, 1)
  __builtin_amdgcn_s_setprio(1);
  QUAD(aN, bF0, 0, 0)
  QUAD(aN, bF1, 0, 1)
  QUAD(aF1, bF1, 1, 1)
  QUAD(aF1, bF0, 1, 0)
  __builtin_amdgcn_s_setprio(0);
#undef LDSA
#undef LDSB
#undef QUAD
#undef RD_A
#undef RD_B

  const float* be = bias + (e << 10);
  float bv[4];
  #pragma unroll
  for (int nf = 0; nf < 4; ++nf) bv[nf] = be[bn0 + (wn << 6) + (nf << 4) + l15];
  #pragma unroll
  for (int mf = 0; mf < 8; ++mf) {
    int rbase = (wm << 7) + (mf << 4) + (hk << 2);
    #pragma unroll
    for (int r = 0; r < 4; ++r) {
      int row = rbase + r;
      if (row < rows_valid) {
        float wv = wrow[row];
        if (use_ybuf) {
          size_t obase = ((size_t)(slot0 + row) << 10);
          #pragma unroll
          for (int nf = 0; nf < 4; ++nf) {        // 4 back-to-back 64B stores per 256B line
            int dout = bn0 + (wn << 6) + (nf << 4) + l15;
            ybuf[obase + dout] = wv * (acc[mf][nf][r] + bv[nf]);
          }
        } else {
          size_t obase = ((size_t)tokid[row] << 10);
          #pragma unroll
          for (int nf = 0; nf < 4; ++nf) {
            int dout = bn0 + (wn << 6) + (nf << 4) + l15;
            atomicAdd(&out[obase + dout], wv * (acc[mf][nf][r] + bv[nf]));
          }
        }
      }
    }
  }
}

// ---------------- combine: out[t] = ybuf[slot0(t)] + ybuf[slot1(t)] ----------------
__global__ __launch_bounds__(256) void combine_kernel(
    const float* __restrict__ ybuf, const int* __restrict__ tok_slot, float* __restrict__ out)
{
  int t = blockIdx.x;
  int s0 = tok_slot[t << 1], s1 = tok_slot[(t << 1) + 1];
  const float4* y0 = (const float4*)(ybuf + ((size_t)s0 << 10));
  const float4* y1 = (const float4*)(ybuf + ((size_t)s1 << 10));
  float4 a = y0[threadIdx.x], b = y1[threadIdx.x];
  float4 r; r.x = a.x + b.x; r.y = a.y + b.y; r.z = a.z + b.z; r.w = a.w + b.w;
  ((float4*)(out + ((size_t)t << 10)))[threadIdx.x] = r;
}

extern "C" void kernel_launch(void* const* d_in, const int* in_sizes, int n_in,
                              void* d_out, int out_size, void* d_ws, size_t ws_size,
                              hipStream_t stream) {
  (void)n_in;
  const float* x  = (const float*)d_in[0];
  const float* gw = (const float*)d_in[1];
  const float* ew = (const float*)d_in[2];
  const float* eb = (const float*)d_in[3];
  int T  = in_sizes[0] >> 10;   // 32768
  int T2 = T << 1;              // 65536 slots

  // workspace layout
  char* wsb = (char*)d_ws;
  unsigned short* xb = (unsigned short*)wsb;
  size_t off = (size_t)T * 1024 * 2;                    // x bf16: 64 MB
  unsigned short* wt = (unsigned short*)(wsb + off);
  off += (size_t)8 * 1024 * 1024 * 2;                   // Wt bf16: 16 MB
  int* ctrl = (int*)(wsb + off); off += 256;
  int* tok_e = (int*)(wsb + off); off += (size_t)T2 * 4;
  int* tok_r = (int*)(wsb + off); off += (size_t)T2 * 4;
  float* tok_w = (float*)(wsb + off); off += (size_t)T2 * 4;
  int* slot_token = (int*)(wsb + off); off += (size_t)T2 * 4;
  float* slot_w = (float*)(wsb + off); off += (size_t)T2 * 4;
  int* tok_slot = (int*)(wsb + off); off += (size_t)T2 * 4;
  int* chunkhist = (int*)(wsb + off); off += 2048 * 4;
  int* base = (int*)(wsb + off); off += 2048 * 4;
  float* ybuf = (float*)(wsb + off);
  size_t need = off + (size_t)T2 * 1024 * 4;            // +268 MB
  int use_ybuf = (ws_size >= need) ? 1 : 0;

  float* out = (float*)d_out;

  if (!use_ybuf)
    hipMemsetAsync(d_out, 0, (size_t)out_size * sizeof(float), stream);
  gate_kernel<<<T / 16, 256, 0, stream>>>(x, gw, xb, tok_e, tok_w);
  wconv_kernel<<<dim3(32, 32, 8), 256, 0, stream>>>(ew, wt);
  hist_kernel<<<T2 / 256, 256, 0, stream>>>(tok_e, tok_r, chunkhist);
  scan_kernel<<<1, 512, 0, stream>>>(chunkhist, base, ctrl);
  scatter_kernel<<<T2 / 256, 256, 0, stream>>>(tok_e, tok_r, tok_w, base,
                                               slot_token, slot_w, tok_slot);
  // 264 M-groups (upper bound, padded to x8) x 4 N-blocks
  moe_gemm<<<1056, 512, 0, stream>>>(xb, wt, eb, ctrl, slot_token, slot_w,
                                     ybuf, out, T2, use_ybuf);
  if (use_ybuf)
    combine_kernel<<<T, 256, 0, stream>>>(ybuf, tok_slot, out);
}

// Round 8
// 365.089 us; speedup vs baseline: 1.1201x; 1.1201x over previous
//
#include <hip/hip_runtime.h>
#include <hip/hip_bf16.h>

// MoE top-2, T=32768 tokens, D=1024, E=8.
// Pipeline: gate(4 tok/wave) -> hist -> scan -> scatter(+inverse map) -> wconv
//           -> grouped GEMM (128^2, BK=32, 3-buf ring, 2-deep counted vmcnt, 3 blk/CU) -> combine.

typedef __attribute__((ext_vector_type(8))) short short8_t;
typedef __attribute__((ext_vector_type(4))) float f32x4_t;

#define GLOAD_LDS16(g, l)                                                                     \
  __builtin_amdgcn_global_load_lds((const __attribute__((address_space(1))) unsigned int*)(g), \
                                   (__attribute__((address_space(3))) unsigned int*)(l), 16, 0, 0)

__device__ __forceinline__ unsigned short f2bf(float f) {
  union { __hip_bfloat16 h; unsigned short u; } c;
  c.h = __float2bfloat16(f);
  return c.u;
}

// ---------------- gate: 4 tokens/wave; fp32 logits, top-2 softmax; x -> bf16 ----------------
__global__ __launch_bounds__(256) void gate_kernel(
    const float* __restrict__ x, const float* __restrict__ gw,
    unsigned short* __restrict__ xb,
    int* __restrict__ tok_e, float* __restrict__ tok_w)
{
  int wid = threadIdx.x >> 6, lane = threadIdx.x & 63;
  int t0 = (blockIdx.x << 4) + (wid << 2);              // 4 tokens per wave
  const float4* g4 = (const float4*)gw;                 // gw is [1024][8] row-major
  float lg[4][8] = {};
  #pragma unroll
  for (int c = 0; c < 4; ++c) {
    int d4 = (c << 6) + lane;                           // float4 index within a row
    float4 ga[4], gb[4];
    #pragma unroll
    for (int j = 0; j < 4; ++j) {
      int d = (d4 << 2) + j;
      ga[j] = g4[d << 1];
      gb[j] = g4[(d << 1) + 1];
    }
    #pragma unroll
    for (int t = 0; t < 4; ++t) {                       // reuse gw regs across 4 tokens
      const float4* x4 = (const float4*)(x + ((size_t)(t0 + t) << 10));
      float4 v = x4[d4];
      unsigned long long pk = (unsigned long long)f2bf(v.x)
                            | ((unsigned long long)f2bf(v.y) << 16)
                            | ((unsigned long long)f2bf(v.z) << 32)
                            | ((unsigned long long)f2bf(v.w) << 48);
      ((unsigned long long*)(xb + ((size_t)(t0 + t) << 10)))[d4] = pk;
      float xs[4] = {v.x, v.y, v.z, v.w};
      #pragma unroll
      for (int j = 0; j < 4; ++j) {
        lg[t][0] += xs[j]*ga[j].x; lg[t][1] += xs[j]*ga[j].y;
        lg[t][2] += xs[j]*ga[j].z; lg[t][3] += xs[j]*ga[j].w;
        lg[t][4] += xs[j]*gb[j].x; lg[t][5] += xs[j]*gb[j].y;
        lg[t][6] += xs[j]*gb[j].z; lg[t][7] += xs[j]*gb[j].w;
      }
    }
  }
  #pragma unroll
  for (int t = 0; t < 4; ++t)
    #pragma unroll
    for (int e = 0; e < 8; ++e) {
      float v = lg[t][e];
      #pragma unroll
      for (int s = 32; s > 0; s >>= 1) v += __shfl_xor(v, s, 64);
      lg[t][e] = v;
    }
  if (lane < 4) {                                       // lane t finalizes token t0+t
    int t = t0 + lane;
    float m0 = lg[lane][0], m1 = -3.4e38f; int e0 = 0, e1 = 0;
    #pragma unroll
    for (int e = 1; e < 8; ++e) {                       // strict '>' matches jax top_k ties
      float v = lg[lane][e];
      if (v > m0) { m1 = m0; e1 = e0; m0 = v; e0 = e; }
      else if (v > m1) { m1 = v; e1 = e; }
    }
    float p1 = 1.0f / (1.0f + expf(m0 - m1));
    float p0 = 1.0f - p1;
    int i0 = t << 1;
    tok_e[i0]   = e0; tok_w[i0]   = p0;
    tok_e[i0+1] = e1; tok_w[i0+1] = p1;
  }
}

// ---------------- hist: per-256-entry chunk, LDS histogram + local rank ----------------
__global__ __launch_bounds__(256) void hist_kernel(
    const int* __restrict__ tok_e, int* __restrict__ tok_r, int* __restrict__ chunkhist)
{
  __shared__ int lh[8];
  if (threadIdx.x < 8) lh[threadIdx.x] = 0;
  __syncthreads();
  int i = (blockIdx.x << 8) + threadIdx.x;
  int e = tok_e[i];
  tok_r[i] = atomicAdd(&lh[e], 1);
  __syncthreads();
  if (threadIdx.x < 8) chunkhist[(blockIdx.x << 3) + threadIdx.x] = lh[threadIdx.x];
}

// ---------------- scan: 8 waves, wave e scans expert e across 256 chunks ----------------
__global__ __launch_bounds__(512) void scan_kernel(
    const int* __restrict__ chunkhist, int* __restrict__ base, int* __restrict__ ctrl)
{
  __shared__ int h[2048];
  __shared__ int bx[2048];
  __shared__ int tot[8], eoff[8];
  for (int i = threadIdx.x; i < 2048; i += 512) h[i] = chunkhist[i];
  __syncthreads();
  int wid = threadIdx.x >> 6, lane = threadIdx.x & 63;
  int running = 0;
  #pragma unroll
  for (int b = 0; b < 4; ++b) {
    int c = (b << 6) + lane;
    int orig = h[(c << 3) + wid];
    int v = orig;
    #pragma unroll
    for (int s = 1; s < 64; s <<= 1) {
      int u = __shfl_up(v, s, 64);
      if (lane >= s) v += u;
    }
    bx[(c << 3) + wid] = running + v - orig;            // exclusive, expert-local
    running += __shfl(v, 63, 64);
  }
  if (lane == 0) tot[wid] = running;
  __syncthreads();
  if (threadIdx.x == 0) {
    int off = 0, boff = 0;
    #pragma unroll
    for (int e = 0; e < 8; ++e) {
      ctrl[e] = tot[e];
      ctrl[8 + e] = off; eoff[e] = off; off += tot[e];
      ctrl[16 + e] = boff; boff += (tot[e] + 127) >> 7;  // 128-row M-groups
    }
    ctrl[24] = boff;
  }
  __syncthreads();
  for (int i = threadIdx.x; i < 2048; i += 512) base[i] = bx[i] + eoff[i & 7];
}

// ---------------- scatter (t,k) -> dense slots + inverse map ----------------
__global__ __launch_bounds__(256) void scatter_kernel(
    const int* __restrict__ tok_e, const int* __restrict__ tok_r, const float* __restrict__ tok_w,
    const int* __restrict__ base, int* __restrict__ slot_token, float* __restrict__ slot_w,
    int* __restrict__ tok_slot)
{
  int i = (blockIdx.x << 8) + threadIdx.x;
  int e = tok_e[i];
  int slot = base[((i >> 8) << 3) + e] + tok_r[i];
  slot_token[slot] = i >> 1;
  slot_w[slot] = tok_w[i];
  tok_slot[i] = slot;
}

// ---------------- expert_w fp32 [e][k][n] -> bf16 transposed Wt[e][n][k] ----------------
__global__ __launch_bounds__(256) void wconv_kernel(const float* __restrict__ w,
                                                    unsigned short* __restrict__ wt)
{
  __shared__ float tile[32][33];
  const float* we = w + ((size_t)blockIdx.z << 20);
  unsigned short* wte = wt + ((size_t)blockIdx.z << 20);
  int k0 = blockIdx.x << 5, n0 = blockIdx.y << 5;
  for (int i = threadIdx.x; i < 1024; i += 256) {
    int k = i >> 5, n = i & 31;
    tile[k][n] = we[(size_t)(k0 + k) * 1024 + n0 + n];
  }
  __syncthreads();
  for (int i = threadIdx.x; i < 1024; i += 256) {
    int n = i >> 5, k = i & 31;
    wte[(size_t)(n0 + n) * 1024 + k0 + k] = f2bf(tile[k][n]);
  }
}

// ---------------- grouped GEMM: 128x128, BK=32, 3-buffer ring, 2-deep prefetch ----------
// 3 blocks/CU (49 KB LDS, launch_bounds(256,3)): inter-block TLP absorbs vmcnt/barrier
// stalls (m114/m97 regime). Per tile: stage tile t+2 -> buf (t+2)%3; read frags from
// buf t%3; 16 MFMA; vmcnt(4) (t+1 landed, t+2 in flight); barrier. Never drains to 0
// until the 2-tile tail. LDS slot s of row r holds k-block s^((r>>1)&3) (both-sides
// swizzle; 0 conflicts measured in r3).
__global__ __launch_bounds__(256, 3) void moe_gemm(
    const unsigned short* __restrict__ xb, const unsigned short* __restrict__ wt,
    const float* __restrict__ bias, const int* __restrict__ ctrl,
    const int* __restrict__ slot_token, const float* __restrict__ slot_w,
    float* __restrict__ ybuf, float* __restrict__ out, int total_slots, int use_ybuf)
{
  __shared__ unsigned short Alds[3 * 128 * 32];   // 24 KB: [buf][row][k]
  __shared__ unsigned short Blds[3 * 128 * 32];   // 24 KB
  __shared__ int   tokid[128];
  __shared__ float wrow[128];

  // dispatch map: 8 N-blocks of an M-group share one XCD (d&7)
  int d = blockIdx.x;
  int s_ = d >> 3, xcd = d & 7;
  int by = ((s_ >> 3) << 3) | xcd;                // M-group id
  int bx = s_ & 7;                                // N-block 0..7
  if (by >= ctrl[24]) return;
  int e = 0;
  #pragma unroll
  for (int i = 1; i < 8; ++i) if (by >= ctrl[16 + i]) e = i;
  int mblk = by - ctrl[16 + e];
  int cnt  = ctrl[e];
  int slot0 = ctrl[8 + e] + (mblk << 7);
  int rows_valid = cnt - (mblk << 7); if (rows_valid > 128) rows_valid = 128;

  int tid = threadIdx.x;
  if (tid < 128) {
    int s = slot0 + tid; if (s > total_slots - 1) s = total_slots - 1;
    tokid[tid] = slot_token[s];
    wrow[tid]  = slot_w[s];
  }
  __syncthreads();

  int lane = tid & 63, w = tid >> 6;
  int wr = w >> 1, wc = w & 1;                    // wave grid 2x2, 64x64 out per wave
  int l15 = lane & 15, hk = lane >> 4;
  int bn0 = bx << 7;
  const unsigned short* wte = wt + ((size_t)e << 20);

  // staging: chunk c (16B) -> row c>>2, LDS slot c&3; source k-block (c&3)^((row>>1)&3)
  int c0 = tid, c1 = tid + 256;
  int r0 = c0 >> 2, k0 = (c0 & 3) ^ ((r0 >> 1) & 3);
  int r1 = c1 >> 2, k1 = (c1 & 3) ^ ((r1 >> 1) & 3);
  const unsigned short* gA0 = xb + ((size_t)tokid[r0] << 10) + (k0 << 3);
  const unsigned short* gA1 = xb + ((size_t)tokid[r1] << 10) + (k1 << 3);
  const unsigned short* gB0 = wte + ((size_t)(bn0 + r0) << 10) + (k0 << 3);
  const unsigned short* gB1 = wte + ((size_t)(bn0 + r1) << 10) + (k1 << 3);
  int lo0 = (w << 6) << 3;                        // wave-uniform LDS dests (shorts)
  int lo1 = ((w << 6) + 256) << 3;

  f32x4_t acc[4][4] = {};

#define STAGE(NB, KO)                                                         \
  GLOAD_LDS16(gA0 + (KO), &Alds[(NB) * 4096 + lo0]);                          \
  GLOAD_LDS16(gA1 + (KO), &Alds[(NB) * 4096 + lo1]);                          \
  GLOAD_LDS16(gB0 + (KO), &Blds[(NB) * 4096 + lo0]);                          \
  GLOAD_LDS16(gB1 + (KO), &Blds[(NB) * 4096 + lo1]);

#define COMPUTE(BUF)                                                          \
  { short8_t aF[4], bF[4];                                                    \
    _Pragma("unroll") for (int m = 0; m < 4; ++m) {                           \
      int ar = (wr << 6) + (m << 4) + l15;                                    \
      aF[m] = *(const short8_t*)&Alds[(BUF) * 4096 + (ar << 5) + ((hk ^ ((ar >> 1) & 3)) << 3)]; } \
    _Pragma("unroll") for (int n = 0; n < 4; ++n) {                           \
      int br = (wc << 6) + (n << 4) + l15;                                    \
      bF[n] = *(const short8_t*)&Blds[(BUF) * 4096 + (br << 5) + ((hk ^ ((br >> 1) & 3)) << 3)]; } \
    __builtin_amdgcn_s_setprio(1);                                            \
    _Pragma("unroll") for (int m = 0; m < 4; ++m)                             \
    _Pragma("unroll") for (int n = 0; n < 4; ++n)                             \
      acc[m][n] = __builtin_amdgcn_mfma_f32_16x16x32_bf16(aF[m], bF[n], acc[m][n], 0, 0, 0); \
    __builtin_amdgcn_s_setprio(0); }

#define VM4 asm volatile("s_waitcnt vmcnt(4)" ::: "memory");
#define BARR __builtin_amdgcn_s_barrier();

  // prologue: stage tiles 0 -> buf0, 1 -> buf1; wait tile 0; barrier
  STAGE(0, 0)
  STAGE(1, 32)
  VM4
  BARR
  // main loop: tiles 0..29 (each stages t+2, 2-deep; vmcnt(4) retires t+1)
  for (int i = 0; i < 10; ++i) {
    int t = i * 3;
    STAGE(2, (t + 2) << 5)
    COMPUTE(0)
    VM4
    BARR
    STAGE(0, (t + 3) << 5)
    COMPUTE(1)
    VM4
    BARR
    STAGE(1, (t + 4) << 5)
    COMPUTE(2)
    VM4
    BARR
  }
  // tail: tile 30 (buf0; drain tile 31), tile 31 (buf1)
  COMPUTE(0)
  asm volatile("s_waitcnt vmcnt(0)" ::: "memory");
  BARR
  COMPUTE(1)
#undef STAGE
#undef COMPUTE
#undef VM4
#undef BARR

  const float* be = bias + (e << 10);
  float bv[4];
  #pragma unroll
  for (int nf = 0; nf < 4; ++nf) bv[nf] = be[bn0 + (wc << 6) + (nf << 4) + l15];
  #pragma unroll
  for (int mf = 0; mf < 4; ++mf) {
    int rbase = (wr << 6) + (mf << 4) + (hk << 2);
    #pragma unroll
    for (int r = 0; r < 4; ++r) {
      int row = rbase + r;
      if (row < rows_valid) {
        float wv = wrow[row];
        if (use_ybuf) {
          size_t obase = ((size_t)(slot0 + row) << 10);
          #pragma unroll
          for (int nf = 0; nf < 4; ++nf) {
            int dout = bn0 + (wc << 6) + (nf << 4) + l15;
            ybuf[obase + dout] = wv * (acc[mf][nf][r] + bv[nf]);
          }
        } else {
          size_t obase = ((size_t)tokid[row] << 10);
          #pragma unroll
          for (int nf = 0; nf < 4; ++nf) {
            int dout = bn0 + (wc << 6) + (nf << 4) + l15;
            atomicAdd(&out[obase + dout], wv * (acc[mf][nf][r] + bv[nf]));
          }
        }
      }
    }
  }
}

// ---------------- combine: out[t] = ybuf[slot0(t)] + ybuf[slot1(t)] ----------------
__global__ __launch_bounds__(256) void combine_kernel(
    const float* __restrict__ ybuf, const int* __restrict__ tok_slot, float* __restrict__ out)
{
  int t = blockIdx.x;
  int s0 = tok_slot[t << 1], s1 = tok_slot[(t << 1) + 1];
  const float4* y0 = (const float4*)(ybuf + ((size_t)s0 << 10));
  const float4* y1 = (const float4*)(ybuf + ((size_t)s1 << 10));
  float4 a = y0[threadIdx.x], b = y1[threadIdx.x];
  float4 r; r.x = a.x + b.x; r.y = a.y + b.y; r.z = a.z + b.z; r.w = a.w + b.w;
  ((float4*)(out + ((size_t)t << 10)))[threadIdx.x] = r;
}

extern "C" void kernel_launch(void* const* d_in, const int* in_sizes, int n_in,
                              void* d_out, int out_size, void* d_ws, size_t ws_size,
                              hipStream_t stream) {
  (void)n_in;
  const float* x  = (const float*)d_in[0];
  const float* gw = (const float*)d_in[1];
  const float* ew = (const float*)d_in[2];
  const float* eb = (const float*)d_in[3];
  int T  = in_sizes[0] >> 10;   // 32768
  int T2 = T << 1;              // 65536 slots

  // workspace layout
  char* wsb = (char*)d_ws;
  unsigned short* xb = (unsigned short*)wsb;
  size_t off = (size_t)T * 1024 * 2;                    // x bf16: 64 MB
  unsigned short* wt = (unsigned short*)(wsb + off);
  off += (size_t)8 * 1024 * 1024 * 2;                   // Wt bf16: 16 MB
  int* ctrl = (int*)(wsb + off); off += 256;
  int* tok_e = (int*)(wsb + off); off += (size_t)T2 * 4;
  int* tok_r = (int*)(wsb + off); off += (size_t)T2 * 4;
  float* tok_w = (float*)(wsb + off); off += (size_t)T2 * 4;
  int* slot_token = (int*)(wsb + off); off += (size_t)T2 * 4;
  float* slot_w = (float*)(wsb + off); off += (size_t)T2 * 4;
  int* tok_slot = (int*)(wsb + off); off += (size_t)T2 * 4;
  int* chunkhist = (int*)(wsb + off); off += 2048 * 4;
  int* base = (int*)(wsb + off); off += 2048 * 4;
  float* ybuf = (float*)(wsb + off);
  size_t need = off + (size_t)T2 * 1024 * 4;            // +268 MB
  int use_ybuf = (ws_size >= need) ? 1 : 0;

  float* out = (float*)d_out;

  if (!use_ybuf)
    hipMemsetAsync(d_out, 0, (size_t)out_size * sizeof(float), stream);
  gate_kernel<<<T / 16, 256, 0, stream>>>(x, gw, xb, tok_e, tok_w);
  wconv_kernel<<<dim3(32, 32, 8), 256, 0, stream>>>(ew, wt);
  hist_kernel<<<T2 / 256, 256, 0, stream>>>(tok_e, tok_r, chunkhist);
  scan_kernel<<<1, 512, 0, stream>>>(chunkhist, base, ctrl);
  scatter_kernel<<<T2 / 256, 256, 0, stream>>>(tok_e, tok_r, tok_w, base,
                                               slot_token, slot_w, tok_slot);
  // up to 520 M-groups (128 rows) x 8 N-blocks
  moe_gemm<<<4160, 256, 0, stream>>>(xb, wt, eb, ctrl, slot_token, slot_w,
                                     ybuf, out, T2, use_ybuf);
  if (use_ybuf)
    combine_kernel<<<T, 256, 0, stream>>>(ybuf, tok_slot, out);
}